// Round 1
// baseline (5634.594 us; speedup 1.0000x reference)
//
#include <hip/hip_runtime.h>
#include <cmath>

#define NN 20000
#define NE 320000
#define EHT (NE + NN)          // edges incl self-loops = 340000
#define TT 8
#define HDIM 32
#define EPSF 1e-16f

// ---- workspace layout (float offsets) ----
#define OFF_DEN1 0                         // [T][N][2]
#define OFF_NUM1 (OFF_DEN1 + TT*NN*2)      // [T][N][2]
#define OFF_DEN2 (OFF_NUM1 + TT*NN*2)      // [T][N]
#define OFF_NUM2 (OFF_DEN2 + TT*NN)        // [T][N][32]
#define ZERO_FLOATS (OFF_NUM2 + TT*NN*HDIM)
#define OFF_C    ZERO_FLOATS               // cs1[2], cd1[2]
#define OFF_H2S  (OFF_C + 16)              // [T][N][32]
#define OFF_AS2  (OFF_H2S + TT*NN*HDIM)    // [T][N]
#define OFF_AD2  (OFF_AS2 + TT*NN)         // [T][N]
#define WS_FLOATS (OFF_AD2 + TT*NN)        // ~45.4 MB total

__global__ void k_setup(const float* __restrict__ W1,
                        const float* __restrict__ as1,
                        const float* __restrict__ ad1,
                        float* __restrict__ wsc) {
    __shared__ float ps[64], pd[64];
    int i = threadIdx.x;               // 0..63
    int hd = i >> 5, d = i & 31;
    ps[i] = W1[hd * 32 + d] * as1[hd * 32 + d];
    pd[i] = W1[hd * 32 + d] * ad1[hd * 32 + d];
    __syncthreads();
    if (i < 2) {
        float s = 0.f, t = 0.f;
        for (int k = 0; k < 32; k++) { s += ps[i * 32 + k]; t += pd[i * 32 + k]; }
        wsc[i] = s;       // cs1[hd]
        wsc[2 + i] = t;   // cd1[hd]
    }
}

__global__ __launch_bounds__(256) void k_l1_edges(
        const float* __restrict__ x, const int* __restrict__ ei,
        const float* __restrict__ wsc,
        float* __restrict__ den1, float* __restrict__ num1) {
    int idx = blockIdx.x * 256 + threadIdx.x;
    if (idx >= TT * EHT) return;
    int t = idx / EHT;
    int e = idx - t * EHT;
    int src, dst;
    if (e < NE) {
        const int* b = ei + (size_t)t * 2 * NE;
        src = b[e];
        dst = b[NE + e];
    } else {
        src = dst = e - NE;            // self-loop
    }
    float xs = x[t * NN + src];
    float xd = x[t * NN + dst];
    float cs0 = wsc[0], cs1 = wsc[1], cd0 = wsc[2], cd1 = wsc[3];
    int base = (t * NN + dst) * 2;
    // head 0
    float v0 = xs * cs0 + xd * cd0;
    v0 = v0 > 0.f ? v0 : 0.2f * v0;
    float ex0 = expf(v0);
    atomicAdd(&den1[base + 0], ex0);
    atomicAdd(&num1[base + 0], ex0 * xs);
    // head 1
    float v1 = xs * cs1 + xd * cd1;
    v1 = v1 > 0.f ? v1 : 0.2f * v1;
    float ex1 = expf(v1);
    atomicAdd(&den1[base + 1], ex1);
    atomicAdd(&num1[base + 1], ex1 * xs);
}

__global__ __launch_bounds__(256) void k_l1_node(
        const float* __restrict__ W1, const float* __restrict__ b1,
        const float* __restrict__ W2,
        const float* __restrict__ as2w, const float* __restrict__ ad2w,
        const float* __restrict__ den1, const float* __restrict__ num1,
        float* __restrict__ h2s, float* __restrict__ as2, float* __restrict__ ad2) {
    __shared__ float sW2[64 * 32];
    __shared__ float sW1[64], sb1[64], sas[32], sad[32];
    int tid = threadIdx.x;
    for (int i = tid; i < 64 * 32; i += 256) sW2[i] = W2[i];
    if (tid < 64) { sW1[tid] = W1[tid]; sb1[tid] = b1[tid]; }
    if (tid < 32) { sas[tid] = as2w[tid]; sad[tid] = ad2w[tid]; }
    __syncthreads();
    int idx = blockIdx.x * 256 + tid;
    if (idx >= TT * NN) return;
    float S0 = num1[idx * 2 + 0] / (den1[idx * 2 + 0] + EPSF);
    float S1 = num1[idx * 2 + 1] / (den1[idx * 2 + 1] + EPSF);
    float h1[64];
#pragma unroll
    for (int d = 0; d < 64; d++) {
        float v = sW1[d] * (d < 32 ? S0 : S1) + sb1[d];
        h1[d] = v > 0.f ? v : expf(v) - 1.f;   // ELU
    }
    float a_s = 0.f, a_d = 0.f;
    float* outp = h2s + (size_t)idx * 32;
#pragma unroll 4
    for (int j = 0; j < 32; j++) {
        float acc = 0.f;
#pragma unroll
        for (int d = 0; d < 64; d++) acc += h1[d] * sW2[d * 32 + j];
        outp[j] = acc;
        a_s += acc * sas[j];
        a_d += acc * sad[j];
    }
    as2[idx] = a_s;
    ad2[idx] = a_d;
}

__global__ __launch_bounds__(256) void k_l2_edges(
        const int* __restrict__ ei,
        const float* __restrict__ as2, const float* __restrict__ ad2,
        const float* __restrict__ h2s,
        float* __restrict__ den2, float* __restrict__ num2) {
    int idx = blockIdx.x * 256 + threadIdx.x;
    if (idx >= TT * EHT) return;
    int t = idx / EHT;
    int e = idx - t * EHT;
    int src, dst;
    if (e < NE) {
        const int* b = ei + (size_t)t * 2 * NE;
        src = b[e];
        dst = b[NE + e];
    } else {
        src = dst = e - NE;
    }
    float v = as2[t * NN + src] + ad2[t * NN + dst];
    v = v > 0.f ? v : 0.2f * v;
    float ex = expf(v);
    atomicAdd(&den2[t * NN + dst], ex);
    const float4* hp = (const float4*)(h2s + (size_t)(t * NN + src) * 32);
    float* np = num2 + (size_t)(t * NN + dst) * 32;
#pragma unroll
    for (int k = 0; k < 8; k++) {
        float4 hv = hp[k];
        atomicAdd(np + 4 * k + 0, ex * hv.x);
        atomicAdd(np + 4 * k + 1, ex * hv.y);
        atomicAdd(np + 4 * k + 2, ex * hv.z);
        atomicAdd(np + 4 * k + 3, ex * hv.w);
    }
}

__global__ __launch_bounds__(256) void k_gru(
        const float* __restrict__ den2, const float* __restrict__ num2,
        const float* __restrict__ b2,
        const float* __restrict__ wih, const float* __restrict__ whh,
        const float* __restrict__ bih, const float* __restrict__ bhh,
        const float* __restrict__ fcw, const float* __restrict__ fcb,
        float* __restrict__ out) {
    __shared__ float swih[96 * 32], swhh[96 * 32];
    __shared__ float sbih[96], sbhh[96], sb2[32], sfw[32];
    int tid = threadIdx.x;
    for (int i = tid; i < 96 * 32; i += 256) { swih[i] = wih[i]; swhh[i] = whh[i]; }
    if (tid < 96) { sbih[tid] = bih[tid]; sbhh[tid] = bhh[tid]; }
    if (tid < 32) { sb2[tid] = b2[tid]; sfw[tid] = fcw[tid]; }
    __syncthreads();
    int n = blockIdx.x * 256 + tid;
    if (n >= NN) return;
    float h[32];
#pragma unroll
    for (int j = 0; j < 32; j++) h[j] = 0.f;
    for (int t = 0; t < TT; t++) {
        int idx = t * NN + n;
        float dinv = 1.f / (den2[idx] + EPSF);
        const float* np = num2 + (size_t)idx * 32;
        float e[32];
#pragma unroll
        for (int d = 0; d < 32; d++) {
            float v = np[d] * dinv + sb2[d];
            e[d] = v > 0.f ? v : expf(v) - 1.f;   // ELU -> enc[t][n]
        }
        float r[32];
#pragma unroll 2
        for (int j = 0; j < 32; j++) {
            float ir = sbih[j], hr = sbhh[j];
#pragma unroll
            for (int k = 0; k < 32; k++) {
                ir += swih[j * 32 + k] * e[k];
                hr += swhh[j * 32 + k] * h[k];
            }
            r[j] = 1.f / (1.f + expf(-(ir + hr)));
        }
        float hnew[32];
#pragma unroll 2
        for (int j = 0; j < 32; j++) {
            float iz = sbih[32 + j], hz = sbhh[32 + j];
            float in_ = sbih[64 + j], hn = sbhh[64 + j];
#pragma unroll
            for (int k = 0; k < 32; k++) {
                iz  += swih[(32 + j) * 32 + k] * e[k];
                hz  += swhh[(32 + j) * 32 + k] * h[k];
                in_ += swih[(64 + j) * 32 + k] * e[k];
                hn  += swhh[(64 + j) * 32 + k] * h[k];
            }
            float z = 1.f / (1.f + expf(-(iz + hz)));
            float nn = tanhf(in_ + r[j] * hn);
            hnew[j] = (1.f - z) * nn + z * h[j];
        }
#pragma unroll
        for (int j = 0; j < 32; j++) h[j] = hnew[j];
    }
    float p = fcb[0];
#pragma unroll
    for (int j = 0; j < 32; j++) p += h[j] * sfw[j];
    out[n] = p;
}

extern "C" void kernel_launch(void* const* d_in, const int* in_sizes, int n_in,
                              void* d_out, int out_size, void* d_ws, size_t ws_size,
                              hipStream_t stream) {
    const float* x    = (const float*)d_in[0];
    const int*   ei   = (const int*)d_in[1];
    const float* W1   = (const float*)d_in[2];
    const float* as1  = (const float*)d_in[3];
    const float* ad1  = (const float*)d_in[4];
    const float* b1   = (const float*)d_in[5];
    const float* W2   = (const float*)d_in[6];
    const float* as2w = (const float*)d_in[7];
    const float* ad2w = (const float*)d_in[8];
    const float* b2   = (const float*)d_in[9];
    const float* wih  = (const float*)d_in[10];
    const float* whh  = (const float*)d_in[11];
    const float* bih  = (const float*)d_in[12];
    const float* bhh  = (const float*)d_in[13];
    const float* fcw  = (const float*)d_in[14];
    const float* fcb  = (const float*)d_in[15];
    float* ws  = (float*)d_ws;
    float* out = (float*)d_out;

    // zero the atomic accumulators (den1, num1, den2, num2)
    hipMemsetAsync(ws, 0, (size_t)ZERO_FLOATS * sizeof(float), stream);

    k_setup<<<1, 64, 0, stream>>>(W1, as1, ad1, ws + OFF_C);

    int eblocks = (TT * EHT + 255) / 256;
    k_l1_edges<<<eblocks, 256, 0, stream>>>(x, ei, ws + OFF_C,
                                            ws + OFF_DEN1, ws + OFF_NUM1);

    int nblocks = (TT * NN + 255) / 256;
    k_l1_node<<<nblocks, 256, 0, stream>>>(W1, b1, W2, as2w, ad2w,
                                           ws + OFF_DEN1, ws + OFF_NUM1,
                                           ws + OFF_H2S, ws + OFF_AS2, ws + OFF_AD2);

    k_l2_edges<<<eblocks, 256, 0, stream>>>(ei, ws + OFF_AS2, ws + OFF_AD2,
                                            ws + OFF_H2S, ws + OFF_DEN2, ws + OFF_NUM2);

    k_gru<<<(NN + 255) / 256, 256, 0, stream>>>(ws + OFF_DEN2, ws + OFF_NUM2, b2,
                                                wih, whh, bih, bhh, fcw, fcb, out);
}

// Round 2
// 1348.717 us; speedup vs baseline: 4.1777x; 4.1777x over previous
//
#include <hip/hip_runtime.h>
#include <cmath>

#define NN 20000
#define NE 320000
#define TT 8
#define EPSF 1e-16f

// ---- workspace layout (4-byte word offsets) ----
#define OFF_DEG 0                       // int   [T][N]    (memset to 0)
#define OFF_ROW (OFF_DEG + TT*NN)       // int   [T][N+1]  CSR row starts
#define OFF_CUR (OFF_ROW + TT*(NN+1))   // int   [T][N]    scatter cursors
#define OFF_CSR (OFF_CUR + TT*NN)       // ushort[T][NE] -> TT*NE/2 words
#define OFF_C   (OFF_CSR + TT*NE/2)     // float cs1[2], cd1[2] (+pad)
#define OFF_H2S (OFF_C + 16)            // float [T][N][32] layer-2 pre-agg feats
#define OFF_AS2 (OFF_H2S + TT*NN*32)    // float [T][N]
#define OFF_AD2 (OFF_AS2 + TT*NN)       // float [T][N]
#define WS_WORDS (OFF_AD2 + TT*NN)      // ~28.2 MB

__global__ void k_setup(const float* __restrict__ W1,
                        const float* __restrict__ as1,
                        const float* __restrict__ ad1,
                        float* __restrict__ wsc) {
    __shared__ float ps[64], pd[64];
    int i = threadIdx.x;               // 0..63
    int hd = i >> 5, d = i & 31;
    ps[i] = W1[hd * 32 + d] * as1[hd * 32 + d];
    pd[i] = W1[hd * 32 + d] * ad1[hd * 32 + d];
    __syncthreads();
    if (i < 2) {
        float s = 0.f, t = 0.f;
        for (int k = 0; k < 32; k++) { s += ps[i * 32 + k]; t += pd[i * 32 + k]; }
        wsc[i] = s;       // cs1[hd]
        wsc[2 + i] = t;   // cd1[hd]
    }
}

__global__ __launch_bounds__(256) void k_count(const int* __restrict__ ei,
                                               int* __restrict__ deg) {
    int idx = blockIdx.x * 256 + threadIdx.x;
    if (idx >= TT * NE) return;
    int t = idx / NE, e = idx - t * NE;
    int dst = ei[(size_t)t * 2 * NE + NE + e];
    atomicAdd(&deg[t * NN + dst], 1);
}

__global__ __launch_bounds__(256) void k_scan(const int* __restrict__ deg,
                                              int* __restrict__ row,
                                              int* __restrict__ cur) {
    int t = blockIdx.x;
    __shared__ int sums[256];
    const int C = (NN + 255) / 256;    // 79
    int tid = threadIdx.x;
    int start = tid * C, end = start + C; if (end > NN) end = NN; if (start > NN) start = NN;
    int s = 0;
    for (int i = start; i < end; i++) s += deg[t * NN + i];
    sums[tid] = s;
    __syncthreads();
    if (tid == 0) {
        int acc = 0;
        for (int i = 0; i < 256; i++) { int v = sums[i]; sums[i] = acc; acc += v; }
    }
    __syncthreads();
    int acc = sums[tid];
    for (int i = start; i < end; i++) {
        int d = deg[t * NN + i];
        row[t * (NN + 1) + i] = acc;
        cur[t * NN + i] = acc;
        acc += d;
    }
    if (tid == 255) row[t * (NN + 1) + NN] = acc;   // == NE
}

__global__ __launch_bounds__(256) void k_scatter(const int* __restrict__ ei,
                                                 int* __restrict__ cur,
                                                 unsigned short* __restrict__ csr) {
    int idx = blockIdx.x * 256 + threadIdx.x;
    if (idx >= TT * NE) return;
    int t = idx / NE, e = idx - t * NE;
    int src = ei[(size_t)t * 2 * NE + e];
    int dst = ei[(size_t)t * 2 * NE + NE + e];
    int pos = atomicAdd(&cur[t * NN + dst], 1);
    csr[(size_t)t * NE + pos] = (unsigned short)src;
}

// Fused: layer-1 scalar-softmax gather + h1 -> h2 matvec + layer-2 attn scalars
__global__ __launch_bounds__(256) void k_l1(
        const float* __restrict__ x, const int* __restrict__ row,
        const unsigned short* __restrict__ csr, const float* __restrict__ wsc,
        const float* __restrict__ W1, const float* __restrict__ b1,
        const float* __restrict__ W2,
        const float* __restrict__ as2w, const float* __restrict__ ad2w,
        float* __restrict__ h2s, float* __restrict__ as2, float* __restrict__ ad2) {
    __shared__ float sW2[64 * 32];
    __shared__ float sW1[64], sb1[64], sas[32], sad[32], sc[4];
    int tid = threadIdx.x;
    for (int i = tid; i < 64 * 32; i += 256) sW2[i] = W2[i];
    if (tid < 64) { sW1[tid] = W1[tid]; sb1[tid] = b1[tid]; }
    if (tid < 32) { sas[tid] = as2w[tid]; sad[tid] = ad2w[tid]; }
    if (tid < 4) sc[tid] = wsc[tid];
    __syncthreads();
    int idx = blockIdx.x * 256 + tid;
    if (idx >= TT * NN) return;
    int t = idx / NN, n = idx - t * NN;
    float cs0 = sc[0], cs1 = sc[1], cd0 = sc[2], cd1 = sc[3];
    float xd = x[idx];
    // self-loop term (src == dst == n)
    float v0 = xd * (cs0 + cd0); v0 = v0 > 0.f ? v0 : 0.2f * v0; float ex0 = expf(v0);
    float v1 = xd * (cs1 + cd1); v1 = v1 > 0.f ? v1 : 0.2f * v1; float ex1 = expf(v1);
    float den0 = ex0, den1 = ex1, S0 = ex0 * xd, S1 = ex1 * xd;
    int rs = row[t * (NN + 1) + n], re = row[t * (NN + 1) + n + 1];
    const unsigned short* cp = csr + (size_t)t * NE;
    const float* xp = x + t * NN;
    for (int i = rs; i < re; i++) {
        int src = cp[i];
        float xs = xp[src];
        float u0 = xs * cs0 + xd * cd0; u0 = u0 > 0.f ? u0 : 0.2f * u0; float q0 = expf(u0);
        float u1 = xs * cs1 + xd * cd1; u1 = u1 > 0.f ? u1 : 0.2f * u1; float q1 = expf(u1);
        den0 += q0; S0 += q0 * xs;
        den1 += q1; S1 += q1 * xs;
    }
    S0 /= (den0 + EPSF);
    S1 /= (den1 + EPSF);
    float h1[64];
#pragma unroll
    for (int d = 0; d < 64; d++) {
        float v = sW1[d] * (d < 32 ? S0 : S1) + sb1[d];
        h1[d] = v > 0.f ? v : expf(v) - 1.f;   // ELU
    }
    float a_s = 0.f, a_d = 0.f;
    float acc[32];
#pragma unroll 4
    for (int j = 0; j < 32; j++) {
        float a = 0.f;
#pragma unroll
        for (int d = 0; d < 64; d++) a += h1[d] * sW2[d * 32 + j];
        acc[j] = a;
        a_s += a * sas[j];
        a_d += a * sad[j];
    }
    float4* op = (float4*)(h2s + (size_t)idx * 32);
#pragma unroll
    for (int q = 0; q < 8; q++)
        op[q] = make_float4(acc[4 * q], acc[4 * q + 1], acc[4 * q + 2], acc[4 * q + 3]);
    as2[idx] = a_s;
    ad2[idx] = a_d;
}

// Fused: layer-2 gather-softmax aggregation + GRU over T + FC head.
// 32 lanes per dst node (lane = feature), 8 nodes per 256-thread block.
__global__ __launch_bounds__(256) void k_l2gru(
        const int* __restrict__ row, const unsigned short* __restrict__ csr,
        const float* __restrict__ as2, const float* __restrict__ ad2,
        const float* __restrict__ h2s, const float* __restrict__ b2,
        const float* __restrict__ wih, const float* __restrict__ whh,
        const float* __restrict__ bih, const float* __restrict__ bhh,
        const float* __restrict__ fcw, const float* __restrict__ fcb,
        float* __restrict__ out) {
    __shared__ float swihT[32 * 96];   // [k][row] transposed: lane reads conflict-free
    __shared__ float swhhT[32 * 96];
    __shared__ float sbih[96], sbhh[96], sb2[32], sfw[32];
    __shared__ float e_buf[8][32], h_buf[8][32];
    int tid = threadIdx.x;
    for (int i = tid; i < 32 * 96; i += 256) {
        int k = i / 96, j = i - k * 96;
        swihT[i] = wih[j * 32 + k];
        swhhT[i] = whh[j * 32 + k];
    }
    if (tid < 96) { sbih[tid] = bih[tid]; sbhh[tid] = bhh[tid]; }
    if (tid < 32) { sb2[tid] = b2[tid]; sfw[tid] = fcw[tid]; }
    __syncthreads();
    int g = tid >> 5, lane = tid & 31;
    int n = blockIdx.x * 8 + g;        // 2500*8 == 20000, always in range
    float h = 0.f;
    h_buf[g][lane] = 0.f;
    for (int t = 0; t < TT; t++) {
        int base = t * NN;
        float adn = ad2[base + n];
        // self-loop
        float a0 = as2[base + n];
        float v = a0 + adn; v = v > 0.f ? v : 0.2f * v;
        float ex = expf(v);
        float den = ex;
        float num = ex * h2s[((size_t)(base + n)) * 32 + lane];
        int rs = row[t * (NN + 1) + n], re = row[t * (NN + 1) + n + 1];
        const unsigned short* cp = csr + (size_t)t * NE;
        for (int i = rs; i < re; i++) {
            int src = cp[i];                       // broadcast load
            float a = as2[base + src];             // broadcast load
            float u = a + adn; u = u > 0.f ? u : 0.2f * u;
            float q = expf(u);
            den += q;
            num += q * h2s[((size_t)(base + src)) * 32 + lane];  // 128B coalesced
        }
        float e = num / (den + EPSF) + sb2[lane];
        e = e > 0.f ? e : expf(e) - 1.f;           // ELU -> enc[t][n][lane]
        e_buf[g][lane] = e;
        __syncthreads();
        float ir = sbih[lane], iz = sbih[32 + lane], inn = sbih[64 + lane];
        float hr = sbhh[lane], hz = sbhh[32 + lane], hn = sbhh[64 + lane];
#pragma unroll
        for (int k = 0; k < 32; k++) {
            float ek = e_buf[g][k], hk = h_buf[g][k];
            const float* wi = swihT + k * 96;
            const float* wh = swhhT + k * 96;
            ir += wi[lane] * ek; iz += wi[32 + lane] * ek; inn += wi[64 + lane] * ek;
            hr += wh[lane] * hk; hz += wh[32 + lane] * hk; hn += wh[64 + lane] * hk;
        }
        float r = 1.f / (1.f + expf(-(ir + hr)));
        float z = 1.f / (1.f + expf(-(iz + hz)));
        float nn_ = tanhf(inn + r * hn);
        h = (1.f - z) * nn_ + z * h;
        __syncthreads();                           // protect h_buf overwrite
        h_buf[g][lane] = h;
    }
    float val = h * sfw[lane];
#pragma unroll
    for (int off = 16; off > 0; off >>= 1) val += __shfl_down(val, off, 32);
    if (lane == 0) out[n] = val + fcb[0];
}

extern "C" void kernel_launch(void* const* d_in, const int* in_sizes, int n_in,
                              void* d_out, int out_size, void* d_ws, size_t ws_size,
                              hipStream_t stream) {
    const float* x    = (const float*)d_in[0];
    const int*   ei   = (const int*)d_in[1];
    const float* W1   = (const float*)d_in[2];
    const float* as1  = (const float*)d_in[3];
    const float* ad1  = (const float*)d_in[4];
    const float* b1   = (const float*)d_in[5];
    const float* W2   = (const float*)d_in[6];
    const float* as2w = (const float*)d_in[7];
    const float* ad2w = (const float*)d_in[8];
    const float* b2   = (const float*)d_in[9];
    const float* wih  = (const float*)d_in[10];
    const float* whh  = (const float*)d_in[11];
    const float* bih  = (const float*)d_in[12];
    const float* bhh  = (const float*)d_in[13];
    const float* fcw  = (const float*)d_in[14];
    const float* fcb  = (const float*)d_in[15];
    float* ws  = (float*)d_ws;
    float* out = (float*)d_out;

    int*            deg = (int*)(ws + OFF_DEG);
    int*            rowp = (int*)(ws + OFF_ROW);
    int*            cur = (int*)(ws + OFF_CUR);
    unsigned short* csr = (unsigned short*)(ws + OFF_CSR);

    hipMemsetAsync(deg, 0, (size_t)TT * NN * sizeof(int), stream);

    k_setup<<<1, 64, 0, stream>>>(W1, as1, ad1, ws + OFF_C);

    int eblocks = (TT * NE + 255) / 256;           // 10000
    k_count<<<eblocks, 256, 0, stream>>>(ei, deg);
    k_scan<<<TT, 256, 0, stream>>>(deg, rowp, cur);
    k_scatter<<<eblocks, 256, 0, stream>>>(ei, cur, csr);

    k_l1<<<(TT * NN) / 256, 256, 0, stream>>>(x, rowp, csr, ws + OFF_C,
                                              W1, b1, W2, as2w, ad2w,
                                              ws + OFF_H2S, ws + OFF_AS2, ws + OFF_AD2);

    k_l2gru<<<NN / 8, 256, 0, stream>>>(rowp, csr, ws + OFF_AS2, ws + OFF_AD2,
                                        ws + OFF_H2S, b2, wih, whh, bih, bhh,
                                        fcw, fcb, out);
}

// Round 3
// 605.208 us; speedup vs baseline: 9.3102x; 2.2285x over previous
//
#include <hip/hip_runtime.h>
#include <cmath>

#define NN 20000
#define NE 320000
#define TT 8
#define EPSF 1e-16f

// ---- workspace layout (4-byte word offsets) ----
#define OFF_DEG 0                       // int   [T][N]    (memset to 0)
#define OFF_ROW (OFF_DEG + TT*NN)       // int   [T][N+1]  CSR row starts
#define OFF_CUR (OFF_ROW + TT*(NN+1))   // int   [T][N]    scatter cursors
#define OFF_CSR (OFF_CUR + TT*NN)       // ushort[T][NE] -> TT*NE/2 words
#define OFF_C   (OFF_CSR + TT*NE/2)     // float cs1[2], cd1[2] (+pad)
#define OFF_H2S (OFF_C + 16)            // float [T][N][32] layer-2 pre-agg feats
#define OFF_AS2 (OFF_H2S + TT*NN*32)    // float [T][N]
#define OFF_AD2 (OFF_AS2 + TT*NN)       // float [T][N]
#define OFF_ENC (OFF_AD2 + TT*NN)       // float [T][N][32] encoder outputs
#define WS_WORDS (OFF_ENC + TT*NN*32)   // ~49.8 MB

__global__ void k_setup(const float* __restrict__ W1,
                        const float* __restrict__ as1,
                        const float* __restrict__ ad1,
                        float* __restrict__ wsc) {
    __shared__ float ps[64], pd[64];
    int i = threadIdx.x;               // 0..63
    int hd = i >> 5, d = i & 31;
    ps[i] = W1[hd * 32 + d] * as1[hd * 32 + d];
    pd[i] = W1[hd * 32 + d] * ad1[hd * 32 + d];
    __syncthreads();
    if (i < 2) {
        float s = 0.f, t = 0.f;
        for (int k = 0; k < 32; k++) { s += ps[i * 32 + k]; t += pd[i * 32 + k]; }
        wsc[i] = s;       // cs1[hd]
        wsc[2 + i] = t;   // cd1[hd]
    }
}

__global__ __launch_bounds__(256) void k_count(const int* __restrict__ ei,
                                               int* __restrict__ deg) {
    int idx = blockIdx.x * 256 + threadIdx.x;
    if (idx >= TT * NE) return;
    int t = idx / NE, e = idx - t * NE;
    int dst = ei[(size_t)t * 2 * NE + NE + e];
    atomicAdd(&deg[t * NN + dst], 1);
}

__global__ __launch_bounds__(256) void k_scan(const int* __restrict__ deg,
                                              int* __restrict__ row,
                                              int* __restrict__ cur) {
    int t = blockIdx.x;
    __shared__ int sums[256];
    const int C = (NN + 255) / 256;    // 79
    int tid = threadIdx.x;
    int start = tid * C, end = start + C; if (end > NN) end = NN; if (start > NN) start = NN;
    int s = 0;
    for (int i = start; i < end; i++) s += deg[t * NN + i];
    sums[tid] = s;
    __syncthreads();
    if (tid == 0) {
        int acc = 0;
        for (int i = 0; i < 256; i++) { int v = sums[i]; sums[i] = acc; acc += v; }
    }
    __syncthreads();
    int acc = sums[tid];
    for (int i = start; i < end; i++) {
        int d = deg[t * NN + i];
        row[t * (NN + 1) + i] = acc;
        cur[t * NN + i] = acc;
        acc += d;
    }
    if (tid == 255) row[t * (NN + 1) + NN] = acc;   // == NE
}

__global__ __launch_bounds__(256) void k_scatter(const int* __restrict__ ei,
                                                 int* __restrict__ cur,
                                                 unsigned short* __restrict__ csr) {
    int idx = blockIdx.x * 256 + threadIdx.x;
    if (idx >= TT * NE) return;
    int t = idx / NE, e = idx - t * NE;
    int src = ei[(size_t)t * 2 * NE + e];
    int dst = ei[(size_t)t * 2 * NE + NE + e];
    int pos = atomicAdd(&cur[t * NN + dst], 1);
    csr[(size_t)t * NE + pos] = (unsigned short)src;
}

// Fused: layer-1 scalar-softmax gather + h1 -> h2 matvec + layer-2 attn scalars
__global__ __launch_bounds__(256) void k_l1(
        const float* __restrict__ x, const int* __restrict__ row,
        const unsigned short* __restrict__ csr, const float* __restrict__ wsc,
        const float* __restrict__ W1, const float* __restrict__ b1,
        const float* __restrict__ W2,
        const float* __restrict__ as2w, const float* __restrict__ ad2w,
        float* __restrict__ h2s, float* __restrict__ as2, float* __restrict__ ad2) {
    __shared__ float sW2[64 * 32];
    __shared__ float sW1[64], sb1[64], sas[32], sad[32], sc[4];
    int tid = threadIdx.x;
    for (int i = tid; i < 64 * 32; i += 256) sW2[i] = W2[i];
    if (tid < 64) { sW1[tid] = W1[tid]; sb1[tid] = b1[tid]; }
    if (tid < 32) { sas[tid] = as2w[tid]; sad[tid] = ad2w[tid]; }
    if (tid < 4) sc[tid] = wsc[tid];
    __syncthreads();
    int idx = blockIdx.x * 256 + tid;
    if (idx >= TT * NN) return;
    int t = idx / NN, n = idx - t * NN;
    float cs0 = sc[0], cs1 = sc[1], cd0 = sc[2], cd1 = sc[3];
    float xd = x[idx];
    // self-loop term (src == dst == n)
    float v0 = xd * (cs0 + cd0); v0 = v0 > 0.f ? v0 : 0.2f * v0; float ex0 = expf(v0);
    float v1 = xd * (cs1 + cd1); v1 = v1 > 0.f ? v1 : 0.2f * v1; float ex1 = expf(v1);
    float den0 = ex0, den1 = ex1, S0 = ex0 * xd, S1 = ex1 * xd;
    int rs = row[t * (NN + 1) + n], re = row[t * (NN + 1) + n + 1];
    const unsigned short* cp = csr + (size_t)t * NE;
    const float* xp = x + t * NN;
    int i = rs;
    for (; i + 4 <= re; i += 4) {
        int sA = cp[i], sB = cp[i + 1], sC = cp[i + 2], sD = cp[i + 3];
        float xA = xp[sA], xB = xp[sB], xC = xp[sC], xD = xp[sD];
        float uA0 = xA * cs0 + xd * cd0; uA0 = uA0 > 0.f ? uA0 : 0.2f * uA0; float qA0 = expf(uA0);
        float uB0 = xB * cs0 + xd * cd0; uB0 = uB0 > 0.f ? uB0 : 0.2f * uB0; float qB0 = expf(uB0);
        float uC0 = xC * cs0 + xd * cd0; uC0 = uC0 > 0.f ? uC0 : 0.2f * uC0; float qC0 = expf(uC0);
        float uD0 = xD * cs0 + xd * cd0; uD0 = uD0 > 0.f ? uD0 : 0.2f * uD0; float qD0 = expf(uD0);
        float uA1 = xA * cs1 + xd * cd1; uA1 = uA1 > 0.f ? uA1 : 0.2f * uA1; float qA1 = expf(uA1);
        float uB1 = xB * cs1 + xd * cd1; uB1 = uB1 > 0.f ? uB1 : 0.2f * uB1; float qB1 = expf(uB1);
        float uC1 = xC * cs1 + xd * cd1; uC1 = uC1 > 0.f ? uC1 : 0.2f * uC1; float qC1 = expf(uC1);
        float uD1 = xD * cs1 + xd * cd1; uD1 = uD1 > 0.f ? uD1 : 0.2f * uD1; float qD1 = expf(uD1);
        den0 += (qA0 + qB0) + (qC0 + qD0);
        S0 += qA0 * xA + qB0 * xB + qC0 * xC + qD0 * xD;
        den1 += (qA1 + qB1) + (qC1 + qD1);
        S1 += qA1 * xA + qB1 * xB + qC1 * xC + qD1 * xD;
    }
    for (; i < re; i++) {
        int src = cp[i];
        float xs = xp[src];
        float u0 = xs * cs0 + xd * cd0; u0 = u0 > 0.f ? u0 : 0.2f * u0; float q0 = expf(u0);
        float u1 = xs * cs1 + xd * cd1; u1 = u1 > 0.f ? u1 : 0.2f * u1; float q1 = expf(u1);
        den0 += q0; S0 += q0 * xs;
        den1 += q1; S1 += q1 * xs;
    }
    S0 /= (den0 + EPSF);
    S1 /= (den1 + EPSF);
    float h1[64];
#pragma unroll
    for (int d = 0; d < 64; d++) {
        float v = sW1[d] * (d < 32 ? S0 : S1) + sb1[d];
        h1[d] = v > 0.f ? v : expf(v) - 1.f;   // ELU
    }
    float a_s = 0.f, a_d = 0.f;
    float acc[32];
#pragma unroll 4
    for (int j = 0; j < 32; j++) {
        float a = 0.f;
#pragma unroll
        for (int d = 0; d < 64; d++) a += h1[d] * sW2[d * 32 + j];
        acc[j] = a;
        a_s += a * sas[j];
        a_d += a * sad[j];
    }
    float4* op = (float4*)(h2s + (size_t)idx * 32);
#pragma unroll
    for (int q = 0; q < 8; q++)
        op[q] = make_float4(acc[4 * q], acc[4 * q + 1], acc[4 * q + 2], acc[4 * q + 3]);
    as2[idx] = a_s;
    ad2[idx] = a_d;
}

// Layer-2 gather-softmax aggregation -> enc[t][n][32].
// 32 lanes per (t,dst) pair (lane = feature), 8 pairs per 256-thread block.
// 4-way unrolled gather for memory-level parallelism.
__global__ __launch_bounds__(256) void k_l2(
        const int* __restrict__ row, const unsigned short* __restrict__ csr,
        const float* __restrict__ as2, const float* __restrict__ ad2,
        const float* __restrict__ h2s, const float* __restrict__ b2,
        float* __restrict__ enc) {
    int tid = threadIdx.x;
    int g = tid >> 5, lane = tid & 31;
    int pair = blockIdx.x * 8 + g;     // t-major: pair = t*NN + n; 160000 total
    int t = pair / NN, n = pair - t * NN;
    int base = t * NN;
    float adn = ad2[pair];
    // self-loop
    float v = as2[pair] + adn; v = v > 0.f ? v : 0.2f * v;
    float ex = expf(v);
    float den = ex;
    float num = ex * h2s[(size_t)pair * 32 + lane];
    int rs = row[t * (NN + 1) + n], re = row[t * (NN + 1) + n + 1];
    const unsigned short* cp = csr + (size_t)t * NE;
    int i = rs;
    for (; i + 4 <= re; i += 4) {
        int sA = cp[i], sB = cp[i + 1], sC = cp[i + 2], sD = cp[i + 3];
        float aA = as2[base + sA], aB = as2[base + sB];
        float aC = as2[base + sC], aD = as2[base + sD];
        float hA = h2s[(size_t)(base + sA) * 32 + lane];
        float hB = h2s[(size_t)(base + sB) * 32 + lane];
        float hC = h2s[(size_t)(base + sC) * 32 + lane];
        float hD = h2s[(size_t)(base + sD) * 32 + lane];
        float uA = aA + adn; uA = uA > 0.f ? uA : 0.2f * uA; float qA = expf(uA);
        float uB = aB + adn; uB = uB > 0.f ? uB : 0.2f * uB; float qB = expf(uB);
        float uC = aC + adn; uC = uC > 0.f ? uC : 0.2f * uC; float qC = expf(uC);
        float uD = aD + adn; uD = uD > 0.f ? uD : 0.2f * uD; float qD = expf(uD);
        den += (qA + qB) + (qC + qD);
        num += qA * hA + qB * hB + qC * hC + qD * hD;
    }
    for (; i < re; i++) {
        int src = cp[i];
        float a = as2[base + src];
        float u = a + adn; u = u > 0.f ? u : 0.2f * u;
        float q = expf(u);
        den += q;
        num += q * h2s[(size_t)(base + src) * 32 + lane];
    }
    float e = num / (den + EPSF) + b2[lane];
    e = e > 0.f ? e : expf(e) - 1.f;   // ELU
    enc[(size_t)pair * 32 + lane] = e;
}

// GRU over T + FC head. 32 lanes per node, 8 nodes per block.
__global__ __launch_bounds__(256) void k_gru(
        const float* __restrict__ enc,
        const float* __restrict__ wih, const float* __restrict__ whh,
        const float* __restrict__ bih, const float* __restrict__ bhh,
        const float* __restrict__ fcw, const float* __restrict__ fcb,
        float* __restrict__ out) {
    __shared__ float swihT[32 * 96];   // [k][row] transposed: lane reads conflict-free
    __shared__ float swhhT[32 * 96];
    __shared__ float sbih[96], sbhh[96], sfw[32];
    __shared__ float e_buf[8][32], h_buf[8][32];
    int tid = threadIdx.x;
    for (int i = tid; i < 32 * 96; i += 256) {
        int k = i / 96, j = i - k * 96;
        swihT[i] = wih[j * 32 + k];
        swhhT[i] = whh[j * 32 + k];
    }
    if (tid < 96) { sbih[tid] = bih[tid]; sbhh[tid] = bhh[tid]; }
    if (tid < 32) sfw[tid] = fcw[tid];
    __syncthreads();
    int g = tid >> 5, lane = tid & 31;
    int n = blockIdx.x * 8 + g;        // 2500*8 == 20000
    float h = 0.f;
    h_buf[g][lane] = 0.f;
    for (int t = 0; t < TT; t++) {
        float e = enc[((size_t)(t * NN + n)) * 32 + lane];
        e_buf[g][lane] = e;
        __syncthreads();
        float ir = sbih[lane], iz = sbih[32 + lane], inn = sbih[64 + lane];
        float hr = sbhh[lane], hz = sbhh[32 + lane], hn = sbhh[64 + lane];
#pragma unroll
        for (int k = 0; k < 32; k++) {
            float ek = e_buf[g][k], hk = h_buf[g][k];
            const float* wi = swihT + k * 96;
            const float* wh = swhhT + k * 96;
            ir += wi[lane] * ek; iz += wi[32 + lane] * ek; inn += wi[64 + lane] * ek;
            hr += wh[lane] * hk; hz += wh[32 + lane] * hk; hn += wh[64 + lane] * hk;
        }
        float r = 1.f / (1.f + expf(-(ir + hr)));
        float z = 1.f / (1.f + expf(-(iz + hz)));
        float nn_ = tanhf(inn + r * hn);
        h = (1.f - z) * nn_ + z * h;
        __syncthreads();                // protect h_buf overwrite
        h_buf[g][lane] = h;
    }
    float val = h * sfw[lane];
#pragma unroll
    for (int off = 16; off > 0; off >>= 1) val += __shfl_down(val, off, 32);
    if (lane == 0) out[n] = val + fcb[0];
}

extern "C" void kernel_launch(void* const* d_in, const int* in_sizes, int n_in,
                              void* d_out, int out_size, void* d_ws, size_t ws_size,
                              hipStream_t stream) {
    const float* x    = (const float*)d_in[0];
    const int*   ei   = (const int*)d_in[1];
    const float* W1   = (const float*)d_in[2];
    const float* as1  = (const float*)d_in[3];
    const float* ad1  = (const float*)d_in[4];
    const float* b1   = (const float*)d_in[5];
    const float* W2   = (const float*)d_in[6];
    const float* as2w = (const float*)d_in[7];
    const float* ad2w = (const float*)d_in[8];
    const float* b2   = (const float*)d_in[9];
    const float* wih  = (const float*)d_in[10];
    const float* whh  = (const float*)d_in[11];
    const float* bih  = (const float*)d_in[12];
    const float* bhh  = (const float*)d_in[13];
    const float* fcw  = (const float*)d_in[14];
    const float* fcb  = (const float*)d_in[15];
    float* ws  = (float*)d_ws;
    float* out = (float*)d_out;

    int*            deg  = (int*)(ws + OFF_DEG);
    int*            rowp = (int*)(ws + OFF_ROW);
    int*            cur  = (int*)(ws + OFF_CUR);
    unsigned short* csr  = (unsigned short*)(ws + OFF_CSR);

    hipMemsetAsync(deg, 0, (size_t)TT * NN * sizeof(int), stream);

    k_setup<<<1, 64, 0, stream>>>(W1, as1, ad1, ws + OFF_C);

    int eblocks = (TT * NE + 255) / 256;           // 10000
    k_count<<<eblocks, 256, 0, stream>>>(ei, deg);
    k_scan<<<TT, 256, 0, stream>>>(deg, rowp, cur);
    k_scatter<<<eblocks, 256, 0, stream>>>(ei, cur, csr);

    k_l1<<<(TT * NN) / 256, 256, 0, stream>>>(x, rowp, csr, ws + OFF_C,
                                              W1, b1, W2, as2w, ad2w,
                                              ws + OFF_H2S, ws + OFF_AS2, ws + OFF_AD2);

    k_l2<<<(TT * NN) / 8, 256, 0, stream>>>(rowp, csr, ws + OFF_AS2, ws + OFF_AD2,
                                            ws + OFF_H2S, b2, ws + OFF_ENC);

    k_gru<<<NN / 8, 256, 0, stream>>>(ws + OFF_ENC, wih, whh, bih, bhh,
                                      fcw, fcb, out);
}

// Round 4
// 516.750 us; speedup vs baseline: 10.9039x; 1.1712x over previous
//
#include <hip/hip_runtime.h>
#include <cmath>

#define NN 20000
#define NE 320000
#define TT 8
#define EPSF 1e-16f

// ---- workspace layout (4-byte word offsets) ----
#define OFF_DEG 0                       // int   [T][N]    (memset to 0)
#define OFF_ROW (OFF_DEG + TT*NN)       // int   [T][N+1]  CSR row starts
#define OFF_CUR (OFF_ROW + TT*(NN+1))   // int   [T][N]    scatter cursors
#define OFF_CSR (OFF_CUR + TT*NN)       // ushort[T][NE] -> TT*NE/2 words
#define OFF_H2S (OFF_CSR + TT*NE/2)     // float [T][N][32] layer-2 pre-agg feats
#define OFF_AS2 (OFF_H2S + TT*NN*32)    // float [T][N]
#define OFF_AD2 (OFF_AS2 + TT*NN)       // float [T][N]
#define OFF_ENC (OFF_AD2 + TT*NN)       // float [T][N][32] encoder outputs
#define WS_WORDS (OFF_ENC + TT*NN*32)   // ~49.8 MB

__device__ __forceinline__ float fexp(float x) { return __expf(x); }
__device__ __forceinline__ float fsigmoid(float x) { return 1.f / (1.f + __expf(-x)); }
__device__ __forceinline__ float ftanh(float x) {
    float ax = fabsf(x);
    float e2 = __expf(-2.f * ax);
    float th = (1.f - e2) / (1.f + e2);
    return copysignf(th, x);
}

__global__ __launch_bounds__(256) void k_count(const int* __restrict__ ei,
                                               int* __restrict__ deg) {
    int idx = blockIdx.x * 256 + threadIdx.x;
    if (idx >= TT * NE) return;
    int t = idx / NE, e = idx - t * NE;
    int dst = ei[(size_t)t * 2 * NE + NE + e];
    atomicAdd(&deg[t * NN + dst], 1);
}

__global__ __launch_bounds__(256) void k_scan(const int* __restrict__ deg,
                                              int* __restrict__ row,
                                              int* __restrict__ cur) {
    int t = blockIdx.x;
    __shared__ int sums[256];
    const int C = (NN + 255) / 256;    // 79
    int tid = threadIdx.x;
    int start = tid * C, end = start + C; if (end > NN) end = NN; if (start > NN) start = NN;
    int s = 0;
    for (int i = start; i < end; i++) s += deg[t * NN + i];
    sums[tid] = s;
    __syncthreads();
    if (tid == 0) {
        int acc = 0;
        for (int i = 0; i < 256; i++) { int v = sums[i]; sums[i] = acc; acc += v; }
    }
    __syncthreads();
    int acc = sums[tid];
    for (int i = start; i < end; i++) {
        int d = deg[t * NN + i];
        row[t * (NN + 1) + i] = acc;
        cur[t * NN + i] = acc;
        acc += d;
    }
    if (tid == 255) row[t * (NN + 1) + NN] = acc;   // == NE
}

__global__ __launch_bounds__(256) void k_scatter(const int* __restrict__ ei,
                                                 int* __restrict__ cur,
                                                 unsigned short* __restrict__ csr) {
    int idx = blockIdx.x * 256 + threadIdx.x;
    if (idx >= TT * NE) return;
    int t = idx / NE, e = idx - t * NE;
    int src = ei[(size_t)t * 2 * NE + e];
    int dst = ei[(size_t)t * 2 * NE + NE + e];
    int pos = atomicAdd(&cur[t * NN + dst], 1);
    csr[(size_t)t * NE + pos] = (unsigned short)src;
}

// Fused: layer-1 scalar-softmax gather + h1 -> h2 matvec + layer-2 attn scalars
__global__ __launch_bounds__(256) void k_l1(
        const float* __restrict__ x, const int* __restrict__ row,
        const unsigned short* __restrict__ csr,
        const float* __restrict__ as1, const float* __restrict__ ad1,
        const float* __restrict__ W1, const float* __restrict__ b1,
        const float* __restrict__ W2,
        const float* __restrict__ as2w, const float* __restrict__ ad2w,
        float* __restrict__ h2s, float* __restrict__ as2, float* __restrict__ ad2) {
    __shared__ float sW2[64 * 32];
    __shared__ float sW1[64], sb1[64], sas[32], sad[32], sc[4];
    int tid = threadIdx.x;
    for (int i = tid; i < 64 * 32; i += 256) sW2[i] = W2[i];
    if (tid < 64) { sW1[tid] = W1[tid]; sb1[tid] = b1[tid]; }
    if (tid < 32) { sas[tid] = as2w[tid]; sad[tid] = ad2w[tid]; }
    if (tid < 4) {                      // sc = {cs1_h0, cs1_h1, cd1_h0, cd1_h1}
        int hd = tid & 1;
        const float* att = (tid < 2) ? as1 : ad1;
        float s = 0.f;
        for (int k = 0; k < 32; k++) s += W1[hd * 32 + k] * att[hd * 32 + k];
        sc[tid] = s;
    }
    __syncthreads();
    int idx = blockIdx.x * 256 + tid;
    if (idx >= TT * NN) return;
    int t = idx / NN, n = idx - t * NN;
    float cs0 = sc[0], cs1 = sc[1], cd0 = sc[2], cd1 = sc[3];
    float xd = x[idx];
    // self-loop term (src == dst == n)
    float v0 = xd * (cs0 + cd0); v0 = v0 > 0.f ? v0 : 0.2f * v0; float ex0 = fexp(v0);
    float v1 = xd * (cs1 + cd1); v1 = v1 > 0.f ? v1 : 0.2f * v1; float ex1 = fexp(v1);
    float den0 = ex0, den1 = ex1, S0 = ex0 * xd, S1 = ex1 * xd;
    int rs = row[t * (NN + 1) + n], re = row[t * (NN + 1) + n + 1];
    const unsigned short* cp = csr + (size_t)t * NE;
    const float* xp = x + t * NN;
    int i = rs;
    for (; i + 4 <= re; i += 4) {
        int sA = cp[i], sB = cp[i + 1], sC = cp[i + 2], sD = cp[i + 3];
        float xA = xp[sA], xB = xp[sB], xC = xp[sC], xD = xp[sD];
        float uA0 = xA * cs0 + xd * cd0; uA0 = uA0 > 0.f ? uA0 : 0.2f * uA0; float qA0 = fexp(uA0);
        float uB0 = xB * cs0 + xd * cd0; uB0 = uB0 > 0.f ? uB0 : 0.2f * uB0; float qB0 = fexp(uB0);
        float uC0 = xC * cs0 + xd * cd0; uC0 = uC0 > 0.f ? uC0 : 0.2f * uC0; float qC0 = fexp(uC0);
        float uD0 = xD * cs0 + xd * cd0; uD0 = uD0 > 0.f ? uD0 : 0.2f * uD0; float qD0 = fexp(uD0);
        float uA1 = xA * cs1 + xd * cd1; uA1 = uA1 > 0.f ? uA1 : 0.2f * uA1; float qA1 = fexp(uA1);
        float uB1 = xB * cs1 + xd * cd1; uB1 = uB1 > 0.f ? uB1 : 0.2f * uB1; float qB1 = fexp(uB1);
        float uC1 = xC * cs1 + xd * cd1; uC1 = uC1 > 0.f ? uC1 : 0.2f * uC1; float qC1 = fexp(uC1);
        float uD1 = xD * cs1 + xd * cd1; uD1 = uD1 > 0.f ? uD1 : 0.2f * uD1; float qD1 = fexp(uD1);
        den0 += (qA0 + qB0) + (qC0 + qD0);
        S0 += qA0 * xA + qB0 * xB + qC0 * xC + qD0 * xD;
        den1 += (qA1 + qB1) + (qC1 + qD1);
        S1 += qA1 * xA + qB1 * xB + qC1 * xC + qD1 * xD;
    }
    for (; i < re; i++) {
        int src = cp[i];
        float xs = xp[src];
        float u0 = xs * cs0 + xd * cd0; u0 = u0 > 0.f ? u0 : 0.2f * u0; float q0 = fexp(u0);
        float u1 = xs * cs1 + xd * cd1; u1 = u1 > 0.f ? u1 : 0.2f * u1; float q1 = fexp(u1);
        den0 += q0; S0 += q0 * xs;
        den1 += q1; S1 += q1 * xs;
    }
    S0 /= (den0 + EPSF);
    S1 /= (den1 + EPSF);
    float h1[64];
#pragma unroll
    for (int d = 0; d < 64; d++) {
        float v = sW1[d] * (d < 32 ? S0 : S1) + sb1[d];
        h1[d] = v > 0.f ? v : fexp(v) - 1.f;   // ELU
    }
    float a_s = 0.f, a_d = 0.f;
    float acc[32];
#pragma unroll 4
    for (int j = 0; j < 32; j++) {
        float a = 0.f;
#pragma unroll
        for (int d = 0; d < 64; d++) a += h1[d] * sW2[d * 32 + j];
        acc[j] = a;
        a_s += a * sas[j];
        a_d += a * sad[j];
    }
    float4* op = (float4*)(h2s + (size_t)idx * 32);
#pragma unroll
    for (int q = 0; q < 8; q++)
        op[q] = make_float4(acc[4 * q], acc[4 * q + 1], acc[4 * q + 2], acc[4 * q + 3]);
    as2[idx] = a_s;
    ad2[idx] = a_d;
}

// Layer-2 gather-softmax aggregation -> enc[t][n][32].
// 32 lanes per (t,dst) pair (lane = feature), 8 pairs per 256-thread block.
__global__ __launch_bounds__(256) void k_l2(
        const int* __restrict__ row, const unsigned short* __restrict__ csr,
        const float* __restrict__ as2, const float* __restrict__ ad2,
        const float* __restrict__ h2s, const float* __restrict__ b2,
        float* __restrict__ enc) {
    int tid = threadIdx.x;
    int g = tid >> 5, lane = tid & 31;
    int pair = blockIdx.x * 8 + g;     // t-major: pair = t*NN + n; 160000 total
    int t = pair / NN, n = pair - t * NN;
    int base = t * NN;
    float adn = ad2[pair];
    // self-loop
    float v = as2[pair] + adn; v = v > 0.f ? v : 0.2f * v;
    float ex = fexp(v);
    float den = ex;
    float num = ex * h2s[(size_t)pair * 32 + lane];
    int rs = row[t * (NN + 1) + n], re = row[t * (NN + 1) + n + 1];
    const unsigned short* cp = csr + (size_t)t * NE;
    int i = rs;
    for (; i + 4 <= re; i += 4) {
        int sA = cp[i], sB = cp[i + 1], sC = cp[i + 2], sD = cp[i + 3];
        float aA = as2[base + sA], aB = as2[base + sB];
        float aC = as2[base + sC], aD = as2[base + sD];
        float hA = h2s[(size_t)(base + sA) * 32 + lane];
        float hB = h2s[(size_t)(base + sB) * 32 + lane];
        float hC = h2s[(size_t)(base + sC) * 32 + lane];
        float hD = h2s[(size_t)(base + sD) * 32 + lane];
        float uA = aA + adn; uA = uA > 0.f ? uA : 0.2f * uA; float qA = fexp(uA);
        float uB = aB + adn; uB = uB > 0.f ? uB : 0.2f * uB; float qB = fexp(uB);
        float uC = aC + adn; uC = uC > 0.f ? uC : 0.2f * uC; float qC = fexp(uC);
        float uD = aD + adn; uD = uD > 0.f ? uD : 0.2f * uD; float qD = fexp(uD);
        den += (qA + qB) + (qC + qD);
        num += qA * hA + qB * hB + qC * hC + qD * hD;
    }
    for (; i < re; i++) {
        int src = cp[i];
        float a = as2[base + src];
        float u = a + adn; u = u > 0.f ? u : 0.2f * u;
        float q = fexp(u);
        den += q;
        num += q * h2s[(size_t)(base + src) * 32 + lane];
    }
    float e = num / (den + EPSF) + b2[lane];
    e = e > 0.f ? e : fexp(e) - 1.f;   // ELU
    enc[(size_t)pair * 32 + lane] = e;
}

// GRU over T + FC head. 32 lanes (lane = output j) per group; each group
// handles 4 nodes to amortize weight LDS reads; 8 groups (32 nodes) per block.
// Weights packed per (k,j): float4 {wi_r,wi_z,wi_n,wh_r} + float2 {wh_z,wh_n}.
__global__ __launch_bounds__(256) void k_gru(
        const float* __restrict__ enc,
        const float* __restrict__ wih, const float* __restrict__ whh,
        const float* __restrict__ bih, const float* __restrict__ bhh,
        const float* __restrict__ fcw, const float* __restrict__ fcb,
        float* __restrict__ out) {
    __shared__ float4 wpA[32 * 32];    // [k][j] 16 KB
    __shared__ float2 wpB[32 * 32];    // [k][j]  8 KB
    __shared__ float sbih[96], sbhh[96], sfw[32];
    __shared__ float e_buf[8][4][32], h_buf[8][4][32];   // [group][m][k]
    int tid = threadIdx.x;
    for (int i = tid; i < 1024; i += 256) {
        int k = i >> 5, j = i & 31;
        wpA[i] = make_float4(wih[j * 32 + k], wih[(32 + j) * 32 + k],
                             wih[(64 + j) * 32 + k], whh[j * 32 + k]);
        wpB[i] = make_float2(whh[(32 + j) * 32 + k], whh[(64 + j) * 32 + k]);
    }
    if (tid < 96) { sbih[tid] = bih[tid]; sbhh[tid] = bhh[tid]; }
    if (tid < 32) sfw[tid] = fcw[tid];
    int g = tid >> 5, lane = tid & 31;
    int n0 = blockIdx.x * 32 + g * 4;  // 625 blocks * 32 nodes = 20000
    float bi_r = 0.f, bi_z = 0.f, bi_n = 0.f, bh_r = 0.f, bh_z = 0.f, bh_n = 0.f;
    float h[4];
#pragma unroll
    for (int m = 0; m < 4; m++) { h[m] = 0.f; h_buf[g][m][lane] = 0.f; }
    __syncthreads();
    bi_r = sbih[lane]; bi_z = sbih[32 + lane]; bi_n = sbih[64 + lane];
    bh_r = sbhh[lane]; bh_z = sbhh[32 + lane]; bh_n = sbhh[64 + lane];
    for (int t = 0; t < TT; t++) {
#pragma unroll
        for (int m = 0; m < 4; m++)
            e_buf[g][m][lane] = enc[((size_t)(t * NN + n0 + m)) * 32 + lane];
        __syncthreads();
        float ir[4], iz[4], in_[4], hr[4], hz[4], hn[4];
#pragma unroll
        for (int m = 0; m < 4; m++) {
            ir[m] = bi_r; iz[m] = bi_z; in_[m] = bi_n;
            hr[m] = bh_r; hz[m] = bh_z; hn[m] = bh_n;
        }
#pragma unroll 8
        for (int k = 0; k < 32; k++) {
            float4 wa = wpA[k * 32 + lane];
            float2 wb = wpB[k * 32 + lane];
#pragma unroll
            for (int m = 0; m < 4; m++) {
                float ek = e_buf[g][m][k];
                float hk = h_buf[g][m][k];
                ir[m] += wa.x * ek; iz[m] += wa.y * ek; in_[m] += wa.z * ek;
                hr[m] += wa.w * hk; hz[m] += wb.x * hk; hn[m] += wb.y * hk;
            }
        }
        __syncthreads();               // all h_buf/e_buf reads done
#pragma unroll
        for (int m = 0; m < 4; m++) {
            float r = fsigmoid(ir[m] + hr[m]);
            float z = fsigmoid(iz[m] + hz[m]);
            float nn_ = ftanh(in_[m] + r * hn[m]);
            h[m] = (1.f - z) * nn_ + z * h[m];
            h_buf[g][m][lane] = h[m];
        }
    }
    float fw = sfw[lane], fb = fcb[0];
#pragma unroll
    for (int m = 0; m < 4; m++) {
        float val = h[m] * fw;
#pragma unroll
        for (int off = 16; off > 0; off >>= 1) val += __shfl_down(val, off, 32);
        if (lane == 0) out[n0 + m] = val + fb;
    }
}

extern "C" void kernel_launch(void* const* d_in, const int* in_sizes, int n_in,
                              void* d_out, int out_size, void* d_ws, size_t ws_size,
                              hipStream_t stream) {
    const float* x    = (const float*)d_in[0];
    const int*   ei   = (const int*)d_in[1];
    const float* W1   = (const float*)d_in[2];
    const float* as1  = (const float*)d_in[3];
    const float* ad1  = (const float*)d_in[4];
    const float* b1   = (const float*)d_in[5];
    const float* W2   = (const float*)d_in[6];
    const float* as2w = (const float*)d_in[7];
    const float* ad2w = (const float*)d_in[8];
    const float* b2   = (const float*)d_in[9];
    const float* wih  = (const float*)d_in[10];
    const float* whh  = (const float*)d_in[11];
    const float* bih  = (const float*)d_in[12];
    const float* bhh  = (const float*)d_in[13];
    const float* fcw  = (const float*)d_in[14];
    const float* fcb  = (const float*)d_in[15];
    float* ws  = (float*)d_ws;
    float* out = (float*)d_out;

    int*            deg  = (int*)(ws + OFF_DEG);
    int*            rowp = (int*)(ws + OFF_ROW);
    int*            cur  = (int*)(ws + OFF_CUR);
    unsigned short* csr  = (unsigned short*)(ws + OFF_CSR);

    hipMemsetAsync(deg, 0, (size_t)TT * NN * sizeof(int), stream);

    int eblocks = (TT * NE + 255) / 256;           // 10000
    k_count<<<eblocks, 256, 0, stream>>>(ei, deg);
    k_scan<<<TT, 256, 0, stream>>>(deg, rowp, cur);
    k_scatter<<<eblocks, 256, 0, stream>>>(ei, cur, csr);

    k_l1<<<(TT * NN) / 256, 256, 0, stream>>>(x, rowp, csr, as1, ad1,
                                              W1, b1, W2, as2w, ad2w,
                                              ws + OFF_H2S, ws + OFF_AS2, ws + OFF_AD2);

    k_l2<<<(TT * NN) / 8, 256, 0, stream>>>(rowp, csr, ws + OFF_AS2, ws + OFF_AD2,
                                            ws + OFF_H2S, b2, ws + OFF_ENC);

    k_gru<<<NN / 32, 256, 0, stream>>>(ws + OFF_ENC, wih, whh, bih, bhh,
                                       fcw, fcb, out);
}

// Round 5
// 486.619 us; speedup vs baseline: 11.5791x; 1.0619x over previous
//
#include <hip/hip_runtime.h>
#include <cmath>

#define NN 20000
#define NE 320000
#define TT 8
#define EPSF 1e-16f

// ---- workspace layout (4-byte word offsets) ----
#define OFF_DEG 0                       // int   [T][N]    (memset to 0)
#define OFF_ROW (OFF_DEG + TT*NN)       // int   [T][N+1]  CSR row starts
#define OFF_CUR (OFF_ROW + TT*(NN+1))   // int   [T][N]    scatter cursors
#define OFF_CSR (OFF_CUR + TT*NN)       // ushort[T][NE] -> TT*NE/2 words
#define OFF_H2S (OFF_CSR + TT*NE/2)     // float [T][N][32] layer-2 pre-agg feats
#define OFF_AS2 (OFF_H2S + TT*NN*32)    // float [T][N]
#define OFF_AD2 (OFF_AS2 + TT*NN)       // float [T][N]
#define OFF_ENC (OFF_AD2 + TT*NN)       // float [T][N][32] encoder outputs
#define WS_WORDS (OFF_ENC + TT*NN*32)   // ~49.8 MB

__device__ __forceinline__ float fexp(float x) { return __expf(x); }
__device__ __forceinline__ float fsigmoid(float x) { return 1.f / (1.f + __expf(-x)); }
__device__ __forceinline__ float ftanh(float x) {
    float ax = fabsf(x);
    float e2 = __expf(-2.f * ax);
    float th = (1.f - e2) / (1.f + e2);
    return copysignf(th, x);
}

// t = blockIdx % 8 pins each timestep's working set (deg/cur/csr slices,
// x/h2s/as2 slices: 0.6-2.6 MB each) to one XCD's 4 MB L2.
__global__ __launch_bounds__(256) void k_count(const int* __restrict__ ei,
                                               int* __restrict__ deg) {
    int b = blockIdx.x;
    int t = b & 7, chunk = b >> 3;                 // 1250 chunks * 256 = NE
    int e = chunk * 256 + threadIdx.x;
    int dst = ei[(size_t)t * 2 * NE + NE + e];
    atomicAdd(&deg[t * NN + dst], 1);
}

__global__ __launch_bounds__(256) void k_scan(const int* __restrict__ deg,
                                              int* __restrict__ row,
                                              int* __restrict__ cur) {
    int t = blockIdx.x;
    __shared__ int sums[256];
    const int C = (NN + 255) / 256;    // 79
    int tid = threadIdx.x;
    int start = tid * C, end = start + C; if (end > NN) end = NN; if (start > NN) start = NN;
    int s = 0;
    for (int i = start; i < end; i++) s += deg[t * NN + i];
    sums[tid] = s;
    __syncthreads();
    if (tid == 0) {
        int acc = 0;
        for (int i = 0; i < 256; i++) { int v = sums[i]; sums[i] = acc; acc += v; }
    }
    __syncthreads();
    int acc = sums[tid];
    for (int i = start; i < end; i++) {
        int d = deg[t * NN + i];
        row[t * (NN + 1) + i] = acc;
        cur[t * NN + i] = acc;
        acc += d;
    }
    if (tid == 255) row[t * (NN + 1) + NN] = acc;   // == NE
}

__global__ __launch_bounds__(256) void k_scatter(const int* __restrict__ ei,
                                                 int* __restrict__ cur,
                                                 unsigned short* __restrict__ csr) {
    int b = blockIdx.x;
    int t = b & 7, chunk = b >> 3;
    int e = chunk * 256 + threadIdx.x;
    int src = ei[(size_t)t * 2 * NE + e];
    int dst = ei[(size_t)t * 2 * NE + NE + e];
    int pos = atomicAdd(&cur[t * NN + dst], 1);
    csr[(size_t)t * NE + pos] = (unsigned short)src;
}

// Fused: layer-1 scalar-softmax gather + h1 -> h2 matvec + layer-2 attn scalars
__global__ __launch_bounds__(256) void k_l1(
        const float* __restrict__ x, const int* __restrict__ row,
        const unsigned short* __restrict__ csr,
        const float* __restrict__ as1, const float* __restrict__ ad1,
        const float* __restrict__ W1, const float* __restrict__ b1,
        const float* __restrict__ W2,
        const float* __restrict__ as2w, const float* __restrict__ ad2w,
        float* __restrict__ h2s, float* __restrict__ as2, float* __restrict__ ad2) {
    __shared__ float sW2[64 * 32];
    __shared__ float sW1[64], sb1[64], sas[32], sad[32], sc[4];
    int tid = threadIdx.x;
    for (int i = tid; i < 64 * 32; i += 256) sW2[i] = W2[i];
    if (tid < 64) { sW1[tid] = W1[tid]; sb1[tid] = b1[tid]; }
    if (tid < 32) { sas[tid] = as2w[tid]; sad[tid] = ad2w[tid]; }
    if (tid < 4) {                      // sc = {cs1_h0, cs1_h1, cd1_h0, cd1_h1}
        int hd = tid & 1;
        const float* att = (tid < 2) ? as1 : ad1;
        float s = 0.f;
        for (int k = 0; k < 32; k++) s += W1[hd * 32 + k] * att[hd * 32 + k];
        sc[tid] = s;
    }
    __syncthreads();
    int b = blockIdx.x;
    int t = b & 7, chunk = b >> 3;      // 79 chunks per t
    int n = chunk * 256 + tid;
    if (n >= NN) return;
    int idx = t * NN + n;
    float cs0 = sc[0], cs1 = sc[1], cd0 = sc[2], cd1 = sc[3];
    float xd = x[idx];
    // self-loop term (src == dst == n)
    float v0 = xd * (cs0 + cd0); v0 = v0 > 0.f ? v0 : 0.2f * v0; float ex0 = fexp(v0);
    float v1 = xd * (cs1 + cd1); v1 = v1 > 0.f ? v1 : 0.2f * v1; float ex1 = fexp(v1);
    float den0 = ex0, den1 = ex1, S0 = ex0 * xd, S1 = ex1 * xd;
    int rs = row[t * (NN + 1) + n], re = row[t * (NN + 1) + n + 1];
    const unsigned short* cp = csr + (size_t)t * NE;
    const float* xp = x + t * NN;
    int i = rs;
    for (; i < re && (i & 3); i++) {
        int src = cp[i];
        float xs = xp[src];
        float u0 = xs * cs0 + xd * cd0; u0 = u0 > 0.f ? u0 : 0.2f * u0; float q0 = fexp(u0);
        float u1 = xs * cs1 + xd * cd1; u1 = u1 > 0.f ? u1 : 0.2f * u1; float q1 = fexp(u1);
        den0 += q0; S0 += q0 * xs;
        den1 += q1; S1 += q1 * xs;
    }
    for (; i + 4 <= re; i += 4) {
        ushort4 s4 = *(const ushort4*)(cp + i);    // 8B aligned: i%4==0
        float xA = xp[s4.x], xB = xp[s4.y], xC = xp[s4.z], xD = xp[s4.w];
        float uA0 = xA * cs0 + xd * cd0; uA0 = uA0 > 0.f ? uA0 : 0.2f * uA0; float qA0 = fexp(uA0);
        float uB0 = xB * cs0 + xd * cd0; uB0 = uB0 > 0.f ? uB0 : 0.2f * uB0; float qB0 = fexp(uB0);
        float uC0 = xC * cs0 + xd * cd0; uC0 = uC0 > 0.f ? uC0 : 0.2f * uC0; float qC0 = fexp(uC0);
        float uD0 = xD * cs0 + xd * cd0; uD0 = uD0 > 0.f ? uD0 : 0.2f * uD0; float qD0 = fexp(uD0);
        float uA1 = xA * cs1 + xd * cd1; uA1 = uA1 > 0.f ? uA1 : 0.2f * uA1; float qA1 = fexp(uA1);
        float uB1 = xB * cs1 + xd * cd1; uB1 = uB1 > 0.f ? uB1 : 0.2f * uB1; float qB1 = fexp(uB1);
        float uC1 = xC * cs1 + xd * cd1; uC1 = uC1 > 0.f ? uC1 : 0.2f * uC1; float qC1 = fexp(uC1);
        float uD1 = xD * cs1 + xd * cd1; uD1 = uD1 > 0.f ? uD1 : 0.2f * uD1; float qD1 = fexp(uD1);
        den0 += (qA0 + qB0) + (qC0 + qD0);
        S0 += qA0 * xA + qB0 * xB + qC0 * xC + qD0 * xD;
        den1 += (qA1 + qB1) + (qC1 + qD1);
        S1 += qA1 * xA + qB1 * xB + qC1 * xC + qD1 * xD;
    }
    for (; i < re; i++) {
        int src = cp[i];
        float xs = xp[src];
        float u0 = xs * cs0 + xd * cd0; u0 = u0 > 0.f ? u0 : 0.2f * u0; float q0 = fexp(u0);
        float u1 = xs * cs1 + xd * cd1; u1 = u1 > 0.f ? u1 : 0.2f * u1; float q1 = fexp(u1);
        den0 += q0; S0 += q0 * xs;
        den1 += q1; S1 += q1 * xs;
    }
    S0 /= (den0 + EPSF);
    S1 /= (den1 + EPSF);
    float h1[64];
#pragma unroll
    for (int d = 0; d < 64; d++) {
        float v = sW1[d] * (d < 32 ? S0 : S1) + sb1[d];
        h1[d] = v > 0.f ? v : fexp(v) - 1.f;   // ELU
    }
    float a_s = 0.f, a_d = 0.f;
    float acc[32];
#pragma unroll 4
    for (int j = 0; j < 32; j++) {
        float a = 0.f;
#pragma unroll
        for (int d = 0; d < 64; d++) a += h1[d] * sW2[d * 32 + j];
        acc[j] = a;
        a_s += a * sas[j];
        a_d += a * sad[j];
    }
    float4* op = (float4*)(h2s + (size_t)idx * 32);
#pragma unroll
    for (int q = 0; q < 8; q++)
        op[q] = make_float4(acc[4 * q], acc[4 * q + 1], acc[4 * q + 2], acc[4 * q + 3]);
    as2[idx] = a_s;
    ad2[idx] = a_d;
}

// Layer-2 gather-softmax aggregation -> enc[t][n][32].
// 32 lanes per (t,dst) pair (lane = feature), 8 pairs per 256-thread block.
__global__ __launch_bounds__(256) void k_l2(
        const int* __restrict__ row, const unsigned short* __restrict__ csr,
        const float* __restrict__ as2, const float* __restrict__ ad2,
        const float* __restrict__ h2s, const float* __restrict__ b2,
        float* __restrict__ enc) {
    int tid = threadIdx.x;
    int g = tid >> 5, lane = tid & 31;
    int b = blockIdx.x;
    int t = b & 7, chunk = b >> 3;     // 2500 chunks * 8 nodes = NN
    int n = chunk * 8 + g;
    int pair = t * NN + n;
    int base = t * NN;
    float adn = ad2[pair];
    // self-loop
    float v = as2[pair] + adn; v = v > 0.f ? v : 0.2f * v;
    float ex = fexp(v);
    float den = ex;
    float num = ex * h2s[(size_t)pair * 32 + lane];
    int rs = row[t * (NN + 1) + n], re = row[t * (NN + 1) + n + 1];
    const unsigned short* cp = csr + (size_t)t * NE;
    int i = rs;
    for (; i < re && (i & 3); i++) {
        int src = cp[i];
        float a = as2[base + src];
        float u = a + adn; u = u > 0.f ? u : 0.2f * u;
        float q = fexp(u);
        den += q;
        num += q * h2s[(size_t)(base + src) * 32 + lane];
    }
    for (; i + 4 <= re; i += 4) {
        ushort4 s4 = *(const ushort4*)(cp + i);
        float aA = as2[base + s4.x], aB = as2[base + s4.y];
        float aC = as2[base + s4.z], aD = as2[base + s4.w];
        float hA = h2s[(size_t)(base + s4.x) * 32 + lane];
        float hB = h2s[(size_t)(base + s4.y) * 32 + lane];
        float hC = h2s[(size_t)(base + s4.z) * 32 + lane];
        float hD = h2s[(size_t)(base + s4.w) * 32 + lane];
        float uA = aA + adn; uA = uA > 0.f ? uA : 0.2f * uA; float qA = fexp(uA);
        float uB = aB + adn; uB = uB > 0.f ? uB : 0.2f * uB; float qB = fexp(uB);
        float uC = aC + adn; uC = uC > 0.f ? uC : 0.2f * uC; float qC = fexp(uC);
        float uD = aD + adn; uD = uD > 0.f ? uD : 0.2f * uD; float qD = fexp(uD);
        den += (qA + qB) + (qC + qD);
        num += qA * hA + qB * hB + qC * hC + qD * hD;
    }
    for (; i < re; i++) {
        int src = cp[i];
        float a = as2[base + src];
        float u = a + adn; u = u > 0.f ? u : 0.2f * u;
        float q = fexp(u);
        den += q;
        num += q * h2s[(size_t)(base + src) * 32 + lane];
    }
    float e = num / (den + EPSF) + b2[lane];
    e = e > 0.f ? e : fexp(e) - 1.f;   // ELU
    enc[(size_t)pair * 32 + lane] = e;
}

// GRU over T + FC head. 32 lanes (lane = output j) per group; each group
// handles 4 nodes to amortize weight LDS reads; 8 groups (32 nodes) per block.
// Weights packed per (k,j): float4 {wi_r,wi_z,wi_n,wh_r} + float2 {wh_z,wh_n}.
__global__ __launch_bounds__(256) void k_gru(
        const float* __restrict__ enc,
        const float* __restrict__ wih, const float* __restrict__ whh,
        const float* __restrict__ bih, const float* __restrict__ bhh,
        const float* __restrict__ fcw, const float* __restrict__ fcb,
        float* __restrict__ out) {
    __shared__ float4 wpA[32 * 32];    // [k][j] 16 KB
    __shared__ float2 wpB[32 * 32];    // [k][j]  8 KB
    __shared__ float sbih[96], sbhh[96], sfw[32];
    __shared__ float e_buf[8][4][32], h_buf[8][4][32];   // [group][m][k]
    int tid = threadIdx.x;
    for (int i = tid; i < 1024; i += 256) {
        int k = i >> 5, j = i & 31;
        wpA[i] = make_float4(wih[j * 32 + k], wih[(32 + j) * 32 + k],
                             wih[(64 + j) * 32 + k], whh[j * 32 + k]);
        wpB[i] = make_float2(whh[(32 + j) * 32 + k], whh[(64 + j) * 32 + k]);
    }
    if (tid < 96) { sbih[tid] = bih[tid]; sbhh[tid] = bhh[tid]; }
    if (tid < 32) sfw[tid] = fcw[tid];
    int g = tid >> 5, lane = tid & 31;
    int n0 = blockIdx.x * 32 + g * 4;  // 625 blocks * 32 nodes = 20000
    float h[4];
#pragma unroll
    for (int m = 0; m < 4; m++) { h[m] = 0.f; h_buf[g][m][lane] = 0.f; }
    __syncthreads();
    float bi_r = sbih[lane], bi_z = sbih[32 + lane], bi_n = sbih[64 + lane];
    float bh_r = sbhh[lane], bh_z = sbhh[32 + lane], bh_n = sbhh[64 + lane];
    for (int t = 0; t < TT; t++) {
#pragma unroll
        for (int m = 0; m < 4; m++)
            e_buf[g][m][lane] = enc[((size_t)(t * NN + n0 + m)) * 32 + lane];
        __syncthreads();
        float ir[4], iz[4], in_[4], hr[4], hz[4], hn[4];
#pragma unroll
        for (int m = 0; m < 4; m++) {
            ir[m] = bi_r; iz[m] = bi_z; in_[m] = bi_n;
            hr[m] = bh_r; hz[m] = bh_z; hn[m] = bh_n;
        }
#pragma unroll 8
        for (int k = 0; k < 32; k++) {
            float4 wa = wpA[k * 32 + lane];
            float2 wb = wpB[k * 32 + lane];
#pragma unroll
            for (int m = 0; m < 4; m++) {
                float ek = e_buf[g][m][k];
                float hk = h_buf[g][m][k];
                ir[m] += wa.x * ek; iz[m] += wa.y * ek; in_[m] += wa.z * ek;
                hr[m] += wa.w * hk; hz[m] += wb.x * hk; hn[m] += wb.y * hk;
            }
        }
        __syncthreads();               // all h_buf/e_buf reads done
#pragma unroll
        for (int m = 0; m < 4; m++) {
            float r = fsigmoid(ir[m] + hr[m]);
            float z = fsigmoid(iz[m] + hz[m]);
            float nn_ = ftanh(in_[m] + r * hn[m]);
            h[m] = (1.f - z) * nn_ + z * h[m];
            h_buf[g][m][lane] = h[m];
        }
    }
    float fw = sfw[lane], fb = fcb[0];
#pragma unroll
    for (int m = 0; m < 4; m++) {
        float val = h[m] * fw;
#pragma unroll
        for (int off = 16; off > 0; off >>= 1) val += __shfl_down(val, off, 32);
        if (lane == 0) out[n0 + m] = val + fb;
    }
}

extern "C" void kernel_launch(void* const* d_in, const int* in_sizes, int n_in,
                              void* d_out, int out_size, void* d_ws, size_t ws_size,
                              hipStream_t stream) {
    const float* x    = (const float*)d_in[0];
    const int*   ei   = (const int*)d_in[1];
    const float* W1   = (const float*)d_in[2];
    const float* as1  = (const float*)d_in[3];
    const float* ad1  = (const float*)d_in[4];
    const float* b1   = (const float*)d_in[5];
    const float* W2   = (const float*)d_in[6];
    const float* as2w = (const float*)d_in[7];
    const float* ad2w = (const float*)d_in[8];
    const float* b2   = (const float*)d_in[9];
    const float* wih  = (const float*)d_in[10];
    const float* whh  = (const float*)d_in[11];
    const float* bih  = (const float*)d_in[12];
    const float* bhh  = (const float*)d_in[13];
    const float* fcw  = (const float*)d_in[14];
    const float* fcb  = (const float*)d_in[15];
    float* ws  = (float*)d_ws;
    float* out = (float*)d_out;

    int*            deg  = (int*)(ws + OFF_DEG);
    int*            rowp = (int*)(ws + OFF_ROW);
    int*            cur  = (int*)(ws + OFF_CUR);
    unsigned short* csr  = (unsigned short*)(ws + OFF_CSR);

    hipMemsetAsync(deg, 0, (size_t)TT * NN * sizeof(int), stream);

    k_count<<<TT * (NE / 256), 256, 0, stream>>>(ei, deg);      // 10000 blocks
    k_scan<<<TT, 256, 0, stream>>>(deg, rowp, cur);
    k_scatter<<<TT * (NE / 256), 256, 0, stream>>>(ei, cur, csr);

    k_l1<<<TT * ((NN + 255) / 256), 256, 0, stream>>>(x, rowp, csr, as1, ad1,
                                              W1, b1, W2, as2w, ad2w,
                                              ws + OFF_H2S, ws + OFF_AS2, ws + OFF_AD2);

    k_l2<<<TT * (NN / 8), 256, 0, stream>>>(rowp, csr, ws + OFF_AS2, ws + OFF_AD2,
                                            ws + OFF_H2S, b2, ws + OFF_ENC);

    k_gru<<<NN / 32, 256, 0, stream>>>(ws + OFF_ENC, wih, whh, bih, bhh,
                                       fcw, fcb, out);
}